// Round 11
// baseline (837.398 us; speedup 1.0000x reference)
//
#include <hip/hip_runtime.h>
#include <cstdint>

typedef long long i64;
typedef unsigned int u32;

// ---------------------------------------------------------------------------
// FraudGNN: 2-layer GraphSAGE (mean aggr), N=100K, E=1.6M, d 64->64->2, fp32.
// Rewrite: lin(mean(x)) == mean(lin(x))  -> transform first, aggregate after.
//   XL = x@W1l^T ; XR = x@W1r^T + b1l
//   h  = relu(meanagg(XL) + XR)            (registers only, never stored)
//   HL = h@W2l^T ; HR = h@W2r^T + b2l      (fused into the aggregation kernel)
//   out = meanagg(HL) + HR
//
// r10 postmortem: gather kernel is fabric-BW-bound (FETCH 189MB = 8 XCDs x
// full 25.6MB XL copy through private L2s; unroll 4->8 gained only 3%) ->
// ~58us is its structural floor at fp32. k_csr (~25us) was pure overhead:
// node-exact sorting that mean-aggregation doesn't need.
//
// Round-11: buckets shrink to 128 nodes (782 buckets, ~3 blocks/CU). The
// aggregation kernel consumes bucket-grouped pairs DIRECTLY: fp32 LDS
// accumulator tile acc[128][68] (34.8KB), 16-lane groups gather XL[src]
// (256B coalesced) and ds_add_f32 into acc[dst] - the sort cost hides under
// the memory wall (VALUBusy was 19.7%). k_csr deleted; csr_src traffic gone.
// ---------------------------------------------------------------------------

#define BKT_SHIFT 7          // 128 nodes per bucket
#define BKT_MAX   1024       // LDS array size (NB=782 for N=100000)
#define BKT_CAP   2688       // slots per bucket (mean 2048 + 14 sigma)
#define CHUNK     4096       // edges per bucket block in pass-A
#define EPT       16         // edges staged per thread (256 thr * 16 = 4096)

__device__ __forceinline__ int edge_at(const void* eidx, int is64, size_t i) {
  return is64 ? (int)((const i64*)eidx)[i] : ((const int*)eidx)[i];
}

// --- k_pre: interleaved heterogeneous blocks: blockIdx%3==0 -> bucket pass-A,
//            else GEMM1. grid = 3*nbkt (nbkt=782, ngem=1563).
__global__ __launch_bounds__(256) void k_pre(const void* __restrict__ eidx,
                                             int* __restrict__ gcount, u32* __restrict__ pairs, int E,
                                             const float* __restrict__ x,
                                             const float* __restrict__ Wl, const float* __restrict__ bl,
                                             const float* __restrict__ Wr,
                                             float* __restrict__ XL, float* __restrict__ XR,
                                             int n_nodes, int nbkt, int ngem) {
  __shared__ float smem[64 * 68 * 3];          // 52224B, shared by both roles
  int tid = threadIdx.x;
  int bid = blockIdx.x;

  if (bid % 3 == 0) {
    // ---------------- bucket pass-A: in-LDS counting sort ----------------
    int b5 = bid / 3;                          // 0..nbkt-1
    int* hist  = (int*)smem;                   // [BKT_MAX]
    int* lbase = hist + BKT_MAX;               // [BKT_MAX] LDS run base
    int* gbase = lbase + BKT_MAX;              // [BKT_MAX] global run base
    int* run   = gbase + BKT_MAX;              // [BKT_MAX]
    int* nzp   = run + BKT_MAX;                // [1]
    u32* sg    = (u32*)(nzp + 1);              // [CHUNK] gpos per sorted slot
    u32* sv    = sg + CHUNK;                   // [CHUNK] packed val per slot
    for (int i = tid; i < BKT_MAX; i += 256) { hist[i] = 0; run[i] = 0; }
    if (tid == 0) *nzp = 0;
    __syncthreads();
    // inline dtype probe: int64 layout => odd 32-bit words all zero
    if (((const int*)eidx)[2 * tid + 1] != 0) *nzp = 1;
    __syncthreads();
    int is64 = (*nzp == 0);

    int cbase = b5 * CHUNK;
    int sreg[EPT], dreg[EPT];
#pragma unroll
    for (int i = 0; i < EPT; ++i) {            // stage 16 edges/thread in regs
      int e = cbase + tid + 256 * i;
      bool v = e < E;
      sreg[i] = v ? edge_at(eidx, is64, (size_t)e) : 0;
      dreg[i] = v ? edge_at(eidx, is64, (size_t)E + e) : -1;
      if (v) atomicAdd(&hist[dreg[i] >> BKT_SHIFT], 1);
    }
    __syncthreads();
    // exclusive scan over 1024 buckets (each thread owns 4); scratch in sv.
    int h0 = hist[4 * tid], h1 = hist[4 * tid + 1];
    int h2 = hist[4 * tid + 2], h3 = hist[4 * tid + 3];
    int ps = h0 + h1 + h2 + h3;
    int* sc = (int*)sv;
    sc[tid] = ps;
    __syncthreads();
    for (int off = 1; off < 256; off <<= 1) {
      int a = (tid >= off) ? sc[tid - off] : 0;
      __syncthreads();
      sc[tid] += a;
      __syncthreads();
    }
    int excl = sc[tid] - ps;
    lbase[4 * tid]     = excl;
    lbase[4 * tid + 1] = excl + h0;
    lbase[4 * tid + 2] = excl + h0 + h1;
    lbase[4 * tid + 3] = excl + h0 + h1 + h2;
    gbase[4 * tid]     = h0 ? (4 * tid) * BKT_CAP + atomicAdd(&gcount[4 * tid], h0) : 0;
    gbase[4 * tid + 1] = h1 ? (4 * tid + 1) * BKT_CAP + atomicAdd(&gcount[4 * tid + 1], h1) : 0;
    gbase[4 * tid + 2] = h2 ? (4 * tid + 2) * BKT_CAP + atomicAdd(&gcount[4 * tid + 2], h2) : 0;
    gbase[4 * tid + 3] = h3 ? (4 * tid + 3) * BKT_CAP + atomicAdd(&gcount[4 * tid + 3], h3) : 0;
    __syncthreads();                           // sc reads done; sv reusable
    // LDS scatter into bucket-sorted order
#pragma unroll
    for (int i = 0; i < EPT; ++i) {
      if (dreg[i] >= 0) {
        int b = dreg[i] >> BKT_SHIFT;
        int r = atomicAdd(&run[b], 1);
        int p = lbase[b] + r;
        sg[p] = gbase[b] + r;
        sv[p] = ((u32)sreg[i] << BKT_SHIFT) | (u32)(dreg[i] & (  (1 << BKT_SHIFT) - 1));
      }
    }
    __syncthreads();
    // linear writeout: consecutive lanes -> consecutive gpos within runs
    int total = min(E - cbase, CHUNK);
    for (int i = tid; i < total; i += 256)
      pairs[sg[i]] = sv[i];
    return;
  }

  // ---------------- GEMM1: XL = x@Wl^T, XR = x@Wr^T + bl ----------------
  int g = bid - bid / 3 - 1;                   // gemm ordinal (bid%3 != 0)
  if (g >= ngem) return;
  // stride 68 floats: float4-aligned, 2-way bank aliasing (free per m136)
  float* sWl = smem;                           // [64*68]
  float* sWr = smem + 64 * 68;
  float* sX  = smem + 2 * 64 * 68;
  int base = g * 64;

#pragma unroll
  for (int r = 0; r < 4; ++r) {                // weights: 64f x 16 float4
    int idx = tid + 256 * r;
    int f = idx >> 4, c4 = idx & 15;
    float4 wl = *(const float4*)(Wl + f * 64 + c4 * 4);
    float4 wr = *(const float4*)(Wr + f * 64 + c4 * 4);
    sWl[(c4 * 4 + 0) * 68 + f] = wl.x; sWl[(c4 * 4 + 1) * 68 + f] = wl.y;
    sWl[(c4 * 4 + 2) * 68 + f] = wl.z; sWl[(c4 * 4 + 3) * 68 + f] = wl.w;
    sWr[(c4 * 4 + 0) * 68 + f] = wr.x; sWr[(c4 * 4 + 1) * 68 + f] = wr.y;
    sWr[(c4 * 4 + 2) * 68 + f] = wr.z; sWr[(c4 * 4 + 3) * 68 + f] = wr.w;
  }
#pragma unroll
  for (int r = 0; r < 4; ++r) {                // x tile: 64n x 16 float4
    int idx = tid + 256 * r;
    int nn = idx >> 4, c4 = idx & 15;
    int node = base + nn;
    float4 xv = make_float4(0.f, 0.f, 0.f, 0.f);
    if (node < n_nodes) xv = *(const float4*)(x + (size_t)node * 64 + c4 * 4);
    sX[(c4 * 4 + 0) * 68 + nn] = xv.x; sX[(c4 * 4 + 1) * 68 + nn] = xv.y;
    sX[(c4 * 4 + 2) * 68 + nn] = xv.z; sX[(c4 * 4 + 3) * 68 + nn] = xv.w;
  }
  __syncthreads();

  int f0 = (tid & 15) * 4, n0 = (tid >> 4) * 4;
  float accL[4][4] = {{0}}, accR[4][4] = {{0}};
#pragma unroll 8
  for (int k = 0; k < 64; ++k) {
    float4 xv = *(const float4*)&sX[k * 68 + n0];
    float4 wl = *(const float4*)&sWl[k * 68 + f0];
    float4 wr = *(const float4*)&sWr[k * 68 + f0];
    float xn[4] = {xv.x, xv.y, xv.z, xv.w};
    float wlf[4] = {wl.x, wl.y, wl.z, wl.w};
    float wrf[4] = {wr.x, wr.y, wr.z, wr.w};
#pragma unroll
    for (int a = 0; a < 4; ++a)
#pragma unroll
      for (int b = 0; b < 4; ++b) {
        accL[a][b] += xn[a] * wlf[b];
        accR[a][b] += xn[a] * wrf[b];
      }
  }

  float4 blv = *(const float4*)(bl + f0);
#pragma unroll
  for (int a = 0; a < 4; ++a) {
    int node = base + n0 + a;
    if (node >= n_nodes) continue;
    float4 ol = make_float4(accL[a][0], accL[a][1], accL[a][2], accL[a][3]);
    float4 orr = make_float4(accR[a][0] + blv.x, accR[a][1] + blv.y,
                             accR[a][2] + blv.z, accR[a][3] + blv.w);
    *(float4*)(XL + (size_t)node * 64 + f0) = ol;
    *(float4*)(XR + (size_t)node * 64 + f0) = orr;
  }
}

// --- k_agg1: bucket-direct aggregation + GEMM2, no node sort needed --------
// One block per 128-node bucket. acc[128][68] fp32 in LDS; 16-lane groups
// gather XL[src] (256B coalesced) and ds_add_f32 into acc[dst]. Then mean +
// XR + relu + 64->2 projections (shfl_xor reduce) -> HL, HR, deg.
__global__ __launch_bounds__(512) void k_agg1(const int* __restrict__ gcount, const u32* __restrict__ pairs,
                                              const float* __restrict__ XL, const float* __restrict__ XR,
                                              const float* __restrict__ W2l, const float* __restrict__ b2l,
                                              const float* __restrict__ W2r,
                                              float* __restrict__ HL, float* __restrict__ HR,
                                              int* __restrict__ degout, int n_nodes) {
  __shared__ float acc[128 * 68];              // 34816B (stride 68: bank-spread)
  __shared__ int degc[128];
  int b = blockIdx.x, t = threadIdx.x;
  for (int i = t; i < 128 * 68; i += 512) acc[i] = 0.f;
  if (t < 128) degc[t] = 0;
  __syncthreads();

  int n = gcount[b];
  int lo = b * BKT_CAP;
  int g = t >> 4, c = t & 15;                  // 32 groups x 16 lanes
  int i = g;
  for (; i + 32 < n; i += 64) {                // unroll-2: 2 outstanding rows
    u32 pa = pairs[lo + i];
    u32 pb = pairs[lo + i + 32];
    int sa = (int)(pa >> BKT_SHIFT), da = (int)(pa & 127);
    int sb = (int)(pb >> BKT_SHIFT), db = (int)(pb & 127);
    float4 va = *(const float4*)(XL + (size_t)sa * 64 + c * 4);
    float4 vb = *(const float4*)(XL + (size_t)sb * 64 + c * 4);
    float* aa = &acc[da * 68 + c * 4];
    atomicAdd(aa + 0, va.x); atomicAdd(aa + 1, va.y);
    atomicAdd(aa + 2, va.z); atomicAdd(aa + 3, va.w);
    float* ab = &acc[db * 68 + c * 4];
    atomicAdd(ab + 0, vb.x); atomicAdd(ab + 1, vb.y);
    atomicAdd(ab + 2, vb.z); atomicAdd(ab + 3, vb.w);
    if (c == 0) { atomicAdd(&degc[da], 1); atomicAdd(&degc[db], 1); }
  }
  if (i < n) {
    u32 pa = pairs[lo + i];
    int sa = (int)(pa >> BKT_SHIFT), da = (int)(pa & 127);
    float4 va = *(const float4*)(XL + (size_t)sa * 64 + c * 4);
    float* aa = &acc[da * 68 + c * 4];
    atomicAdd(aa + 0, va.x); atomicAdd(aa + 1, va.y);
    atomicAdd(aa + 2, va.z); atomicAdd(aa + 3, va.w);
    if (c == 0) atomicAdd(&degc[da], 1);
  }
  __syncthreads();

  // finish: 32 groups x 4 rounds cover 128 nodes (group-uniform branches)
  float4 wl0 = *(const float4*)(W2l + c * 4);
  float4 wl1 = *(const float4*)(W2l + 64 + c * 4);
  float4 wr0 = *(const float4*)(W2r + c * 4);
  float4 wr1 = *(const float4*)(W2r + 64 + c * 4);
#pragma unroll
  for (int r = 0; r < 4; ++r) {
    int dn = r * 32 + g;
    int node = (b << BKT_SHIFT) + dn;
    if (node >= n_nodes) continue;
    int deg = degc[dn];
    float inv = 1.0f / fmaxf((float)deg, 1.0f);
    float4 a = *(float4*)&acc[dn * 68 + c * 4];
    float4 xr = *(const float4*)(XR + (size_t)node * 64 + c * 4);
    float4 h;
    h.x = fmaxf(a.x * inv + xr.x, 0.f);
    h.y = fmaxf(a.y * inv + xr.y, 0.f);
    h.z = fmaxf(a.z * inv + xr.z, 0.f);
    h.w = fmaxf(a.w * inv + xr.w, 0.f);
    float p0 = h.x * wl0.x + h.y * wl0.y + h.z * wl0.z + h.w * wl0.w;
    float p1 = h.x * wl1.x + h.y * wl1.y + h.z * wl1.z + h.w * wl1.w;
    float q0 = h.x * wr0.x + h.y * wr0.y + h.z * wr0.z + h.w * wr0.w;
    float q1 = h.x * wr1.x + h.y * wr1.y + h.z * wr1.z + h.w * wr1.w;
#pragma unroll
    for (int off = 1; off < 16; off <<= 1) {
      p0 += __shfl_xor(p0, off, 16);
      p1 += __shfl_xor(p1, off, 16);
      q0 += __shfl_xor(q0, off, 16);
      q1 += __shfl_xor(q1, off, 16);
    }
    if (c == 0) {
      *(float2*)(HL + (size_t)node * 2) = make_float2(p0, p1);
      *(float2*)(HR + (size_t)node * 2) = make_float2(q0 + b2l[0], q1 + b2l[1]);
      degout[node] = deg;
    }
  }
}

// --- k_agg2: bucket-direct 2-dim aggregation -------------------------------
__global__ __launch_bounds__(256) void k_agg2(const int* __restrict__ gcount, const u32* __restrict__ pairs,
                                              const float* __restrict__ HL, const float* __restrict__ HR,
                                              const int* __restrict__ degout,
                                              float* __restrict__ out, int n_nodes) {
  __shared__ float a0[128];
  __shared__ float a1[128];
  int b = blockIdx.x, t = threadIdx.x;
  if (t < 128) { a0[t] = 0.f; a1[t] = 0.f; }
  __syncthreads();
  int n = gcount[b];
  int lo = b * BKT_CAP;
  for (int i = t; i < n; i += 256) {
    u32 p = pairs[lo + i];
    int s = (int)(p >> BKT_SHIFT), d = (int)(p & 127);
    float2 v = *(const float2*)(HL + (size_t)s * 2);
    atomicAdd(&a0[d], v.x);
    atomicAdd(&a1[d], v.y);
  }
  __syncthreads();
  if (t < 128) {
    int node = (b << BKT_SHIFT) + t;
    if (node < n_nodes) {
      float inv = 1.0f / fmaxf((float)degout[node], 1.0f);
      float2 hr = *(const float2*)(HR + (size_t)node * 2);
      out[node * 2 + 0] = a0[t] * inv + hr.x;
      out[node * 2 + 1] = a1[t] * inv + hr.y;
    }
  }
}

// ---------------------------------------------------------------------------
extern "C" void kernel_launch(void* const* d_in, const int* in_sizes, int n_in,
                              void* d_out, int out_size, void* d_ws, size_t ws_size,
                              hipStream_t stream) {
  const float* x   = (const float*)d_in[0];
  const void*  eix = d_in[1];
  const float* W1l = (const float*)d_in[2];
  const float* b1l = (const float*)d_in[3];
  const float* W1r = (const float*)d_in[4];
  const float* W2l = (const float*)d_in[5];
  const float* b2l = (const float*)d_in[6];
  const float* W2r = (const float*)d_in[7];
  float* out = (float*)d_out;

  const int N = in_sizes[0] / 64;              // 100000
  const int E = in_sizes[1] / 2;               // 1600000
  const int NB = (N + 127) >> BKT_SHIFT;       // 782 buckets

  // workspace layout (256B-aligned chunks)
  char* base = (char*)d_ws;
  size_t off = 0;
  auto alloc = [&](size_t bytes) {
    char* p = base + off;
    off = (off + bytes + 255) & ~(size_t)255;
    return p;
  };
  int*   gcount  = (int*)alloc((size_t)BKT_MAX * 4);
  int*   degout  = (int*)alloc((size_t)N * 4);
  u32*   pairs   = (u32*)alloc((size_t)NB * BKT_CAP * 4);   // 8.4 MB
  float* XL      = (float*)alloc((size_t)N * 64 * 4);
  float* XR      = (float*)alloc((size_t)N * 64 * 4);
  float* HL      = (float*)alloc((size_t)N * 2 * 4);
  float* HR      = (float*)alloc((size_t)N * 2 * 4);
  (void)ws_size;

  const int nbkt = (E + CHUNK - 1) / CHUNK;    // 391 pass-A blocks... (E/4096)
  const int ngem = (N + 63) / 64;              // 1563 gemm blocks

  hipMemsetAsync(gcount, 0, (size_t)BKT_MAX * 4, stream);
  // grid: interleave 1 bucket : 2 gemm -> bid%3. nbkt=391 < 782: pattern
  // still mixes roles on every CU. Guard both ordinals inside.
  {
    int nb3 = 3 * ((nbkt > (ngem + 1) / 2) ? nbkt : (ngem + 2) / 2 + 1);
    // ensure enough slots for both roles: buckets need nbkt slots (every 3rd),
    // gemm needs ngem slots (2 of every 3)
    int slots_b = (nb3 + 2) / 3, slots_g = nb3 - slots_b;
    if (slots_b < nbkt || slots_g < ngem) nb3 = 3 * nbkt + (ngem - 2 * nbkt > 0 ? ((ngem - 2 * nbkt + 1) / 2) * 3 : 0);
    // simple safe upper bound:
    nb3 = 3 * ((nbkt > (ngem + 1) / 2 ? nbkt : (ngem + 1) / 2));
    k_pre<<<nb3, 256, 0, stream>>>(eix, gcount, pairs, E,
                                   x, W1l, b1l, W1r, XL, XR, N, nbkt, ngem);
  }
  k_agg1<<<NB, 512, 0, stream>>>(gcount, pairs, XL, XR, W2l, b2l, W2r, HL, HR, degout, N);
  k_agg2<<<NB, 256, 0, stream>>>(gcount, pairs, HL, HR, degout, out, N);
}

// Round 12
// 209.321 us; speedup vs baseline: 4.0005x; 4.0005x over previous
//
#include <hip/hip_runtime.h>
#include <cstdint>

typedef long long i64;
typedef unsigned int u32;

// ---------------------------------------------------------------------------
// FraudGNN: 2-layer GraphSAGE (mean aggr), N=100K, E=1.6M, d 64->64->2, fp32.
// Rewrite: lin(mean(x)) == mean(lin(x))  -> transform first, aggregate after.
//   XL = x@W1l^T ; XR = x@W1r^T + b1l
//   h  = relu(meanagg(XL) + XR)            (registers only, never stored)
//   HL = h@W2l^T ; HR = h@W2r^T + b2l      (fused into the aggregation kernel)
//   out = meanagg(HL) + HR
//
// r11 postmortem (686us agg): LDS-accumulator aggregation serialized the
// gather (2 outstanding loads/group + lgkmcnt-chained ds_add) -> MLP collapse,
// 286GB/s vs 3354GB/s. REVERTED to r10 structure: register accumulation with
// 8 outstanding loads/lane is load-bearing. One change vs r10: buckets 256->
// 128 nodes (NB=782) so k_csr gets ~3 blocks/CU instead of 1.5.
// ---------------------------------------------------------------------------

#define BKT_SHIFT 7          // 128 nodes per bucket
#define BKT_MAX   1024       // LDS array size (NB=782 for N=100000)
#define BKT_CAP   2688       // slots per bucket (mean 2048 + ~14 sigma)
#define CHUNK     4096       // edges per bucket block in pass-A
#define EPT       16         // edges staged per thread (256 thr * 16 = 4096)

__device__ __forceinline__ int edge_at(const void* eidx, int is64, size_t i) {
  return is64 ? (int)((const i64*)eidx)[i] : ((const int*)eidx)[i];
}

// --- k_pre: interleaved heterogeneous blocks: blockIdx%5==0 -> bucket pass-A,
//            else GEMM1. grid = 5*nbkt (nbkt=391, ngem=1563~=4*nbkt).
__global__ __launch_bounds__(256) void k_pre(const void* __restrict__ eidx,
                                             int* __restrict__ gcount, u32* __restrict__ pairs, int E,
                                             const float* __restrict__ x,
                                             const float* __restrict__ Wl, const float* __restrict__ bl,
                                             const float* __restrict__ Wr,
                                             float* __restrict__ XL, float* __restrict__ XR,
                                             int n_nodes, int nbkt, int ngem) {
  __shared__ float smem[64 * 68 * 3];          // 52224B, shared by both roles
  int tid = threadIdx.x;
  int bid = blockIdx.x;

  if (bid % 5 == 0) {
    // ---------------- bucket pass-A: in-LDS counting sort ----------------
    int b5 = bid / 5;                          // 0..nbkt-1
    int* hist  = (int*)smem;                   // [BKT_MAX]
    int* lbase = hist + BKT_MAX;               // [BKT_MAX] LDS run base
    int* gbase = lbase + BKT_MAX;              // [BKT_MAX] global run base
    int* run   = gbase + BKT_MAX;              // [BKT_MAX]
    int* nzp   = run + BKT_MAX;                // [1]
    u32* sg    = (u32*)(nzp + 1);              // [CHUNK] gpos per sorted slot
    u32* sv    = sg + CHUNK;                   // [CHUNK] packed val per slot
    for (int i = tid; i < BKT_MAX; i += 256) { hist[i] = 0; run[i] = 0; }
    if (tid == 0) *nzp = 0;
    __syncthreads();
    // inline dtype probe: int64 layout => odd 32-bit words all zero
    if (((const int*)eidx)[2 * tid + 1] != 0) *nzp = 1;
    __syncthreads();
    int is64 = (*nzp == 0);

    int cbase = b5 * CHUNK;
    int sreg[EPT], dreg[EPT];
#pragma unroll
    for (int i = 0; i < EPT; ++i) {            // stage 16 edges/thread in regs
      int e = cbase + tid + 256 * i;
      bool v = e < E;
      sreg[i] = v ? edge_at(eidx, is64, (size_t)e) : 0;
      dreg[i] = v ? edge_at(eidx, is64, (size_t)E + e) : -1;
      if (v) atomicAdd(&hist[dreg[i] >> BKT_SHIFT], 1);
    }
    __syncthreads();
    // exclusive scan over 1024 bucket slots (each thread owns 4); scratch in sv
    int h0 = hist[4 * tid], h1 = hist[4 * tid + 1];
    int h2 = hist[4 * tid + 2], h3 = hist[4 * tid + 3];
    int ps = h0 + h1 + h2 + h3;
    int* sc = (int*)sv;
    sc[tid] = ps;
    __syncthreads();
    for (int off = 1; off < 256; off <<= 1) {
      int a = (tid >= off) ? sc[tid - off] : 0;
      __syncthreads();
      sc[tid] += a;
      __syncthreads();
    }
    int excl = sc[tid] - ps;
    lbase[4 * tid]     = excl;
    lbase[4 * tid + 1] = excl + h0;
    lbase[4 * tid + 2] = excl + h0 + h1;
    lbase[4 * tid + 3] = excl + h0 + h1 + h2;
    gbase[4 * tid]     = h0 ? (4 * tid) * BKT_CAP + atomicAdd(&gcount[4 * tid], h0) : 0;
    gbase[4 * tid + 1] = h1 ? (4 * tid + 1) * BKT_CAP + atomicAdd(&gcount[4 * tid + 1], h1) : 0;
    gbase[4 * tid + 2] = h2 ? (4 * tid + 2) * BKT_CAP + atomicAdd(&gcount[4 * tid + 2], h2) : 0;
    gbase[4 * tid + 3] = h3 ? (4 * tid + 3) * BKT_CAP + atomicAdd(&gcount[4 * tid + 3], h3) : 0;
    __syncthreads();                           // sc reads done; sv reusable
    // LDS scatter into bucket-sorted order
#pragma unroll
    for (int i = 0; i < EPT; ++i) {
      if (dreg[i] >= 0) {
        int b = dreg[i] >> BKT_SHIFT;
        int r = atomicAdd(&run[b], 1);
        int p = lbase[b] + r;
        sg[p] = gbase[b] + r;
        sv[p] = ((u32)sreg[i] << BKT_SHIFT) | (u32)(dreg[i] & ((1 << BKT_SHIFT) - 1));
      }
    }
    __syncthreads();
    // linear writeout: consecutive lanes -> consecutive gpos within runs
    int total = min(E - cbase, CHUNK);
    for (int i = tid; i < total; i += 256)
      pairs[sg[i]] = sv[i];
    return;
  }

  // ---------------- GEMM1: XL = x@Wl^T, XR = x@Wr^T + bl ----------------
  int g = bid - bid / 5 - 1;                   // gemm ordinal (bid%5 != 0)
  if (g >= ngem) return;
  // stride 68 floats: float4-aligned, 2-way bank aliasing (free per m136)
  float* sWl = smem;                           // [64*68]
  float* sWr = smem + 64 * 68;
  float* sX  = smem + 2 * 64 * 68;
  int base = g * 64;

#pragma unroll
  for (int r = 0; r < 4; ++r) {                // weights: 64f x 16 float4
    int idx = tid + 256 * r;
    int f = idx >> 4, c4 = idx & 15;
    float4 wl = *(const float4*)(Wl + f * 64 + c4 * 4);
    float4 wr = *(const float4*)(Wr + f * 64 + c4 * 4);
    sWl[(c4 * 4 + 0) * 68 + f] = wl.x; sWl[(c4 * 4 + 1) * 68 + f] = wl.y;
    sWl[(c4 * 4 + 2) * 68 + f] = wl.z; sWl[(c4 * 4 + 3) * 68 + f] = wl.w;
    sWr[(c4 * 4 + 0) * 68 + f] = wr.x; sWr[(c4 * 4 + 1) * 68 + f] = wr.y;
    sWr[(c4 * 4 + 2) * 68 + f] = wr.z; sWr[(c4 * 4 + 3) * 68 + f] = wr.w;
  }
#pragma unroll
  for (int r = 0; r < 4; ++r) {                // x tile: 64n x 16 float4
    int idx = tid + 256 * r;
    int nn = idx >> 4, c4 = idx & 15;
    int node = base + nn;
    float4 xv = make_float4(0.f, 0.f, 0.f, 0.f);
    if (node < n_nodes) xv = *(const float4*)(x + (size_t)node * 64 + c4 * 4);
    sX[(c4 * 4 + 0) * 68 + nn] = xv.x; sX[(c4 * 4 + 1) * 68 + nn] = xv.y;
    sX[(c4 * 4 + 2) * 68 + nn] = xv.z; sX[(c4 * 4 + 3) * 68 + nn] = xv.w;
  }
  __syncthreads();

  int f0 = (tid & 15) * 4, n0 = (tid >> 4) * 4;
  float accL[4][4] = {{0}}, accR[4][4] = {{0}};
#pragma unroll 8
  for (int k = 0; k < 64; ++k) {
    float4 xv = *(const float4*)&sX[k * 68 + n0];
    float4 wl = *(const float4*)&sWl[k * 68 + f0];
    float4 wr = *(const float4*)&sWr[k * 68 + f0];
    float xn[4] = {xv.x, xv.y, xv.z, xv.w};
    float wlf[4] = {wl.x, wl.y, wl.z, wl.w};
    float wrf[4] = {wr.x, wr.y, wr.z, wr.w};
#pragma unroll
    for (int a = 0; a < 4; ++a)
#pragma unroll
      for (int b = 0; b < 4; ++b) {
        accL[a][b] += xn[a] * wlf[b];
        accR[a][b] += xn[a] * wrf[b];
      }
  }

  float4 blv = *(const float4*)(bl + f0);
#pragma unroll
  for (int a = 0; a < 4; ++a) {
    int node = base + n0 + a;
    if (node >= n_nodes) continue;
    float4 ol = make_float4(accL[a][0], accL[a][1], accL[a][2], accL[a][3]);
    float4 orr = make_float4(accR[a][0] + blv.x, accR[a][1] + blv.y,
                             accR[a][2] + blv.z, accR[a][3] + blv.w);
    *(float4*)(XL + (size_t)node * 64 + f0) = ol;
    *(float4*)(XR + (size_t)node * 64 + f0) = orr;
  }
}

// --- pass B: one workgroup (512 thr) owns one 128-node bucket --------------
// count -> LDS scan (recovers row_ptr for free) -> single-writer scatter.
__global__ __launch_bounds__(512) void k_csr(const int* __restrict__ gcount, const u32* __restrict__ pairs,
                                             int* __restrict__ csr_src, int* __restrict__ rs,
                                             int* __restrict__ re, int n_nodes) {
  __shared__ int cnt[128];
  __shared__ int sc[128];
  __shared__ int cur[128];
  int b = blockIdx.x, t = threadIdx.x;
  if (t < 128) cnt[t] = 0;
  __syncthreads();
  int n = gcount[b];
  int lo = b * BKT_CAP, hi = lo + n;
  int tail = n & 3;
  const u32 M = (1 << BKT_SHIFT) - 1;
  for (int i = lo + t * 4; i + 3 < hi; i += 2048) {     // uint4: 4 pairs/iter
    uint4 p = *(const uint4*)(pairs + i);
    atomicAdd(&cnt[p.x & M], 1); atomicAdd(&cnt[p.y & M], 1);
    atomicAdd(&cnt[p.z & M], 1); atomicAdd(&cnt[p.w & M], 1);
  }
  if (t < tail) atomicAdd(&cnt[pairs[hi - tail + t] & M], 1);
  __syncthreads();
  int v = (t < 128) ? cnt[t] : 0;
  if (t < 128) sc[t] = v;
  __syncthreads();
  for (int off = 1; off < 128; off <<= 1) {
    int a = (t >= off && t < 128) ? sc[t - off] : 0;
    __syncthreads();
    if (t < 128) sc[t] += a;
    __syncthreads();
  }
  if (t < 128) {
    int start = lo + sc[t] - v;          // bucket-private exclusive scan
    int node = (b << BKT_SHIFT) + t;
    if (node < n_nodes) { rs[node] = start; re[node] = start + v; }
    cur[t] = start;
  }
  __syncthreads();
  for (int i = lo + t * 4; i + 3 < hi; i += 2048) {
    uint4 p = *(const uint4*)(pairs + i);
    csr_src[atomicAdd(&cur[p.x & M], 1)] = (int)(p.x >> BKT_SHIFT);
    csr_src[atomicAdd(&cur[p.y & M], 1)] = (int)(p.y >> BKT_SHIFT);
    csr_src[atomicAdd(&cur[p.z & M], 1)] = (int)(p.z >> BKT_SHIFT);
    csr_src[atomicAdd(&cur[p.w & M], 1)] = (int)(p.w >> BKT_SHIFT);
  }
  if (t < tail) {
    u32 p = pairs[hi - tail + t];
    csr_src[atomicAdd(&cur[p & M], 1)] = (int)(p >> BKT_SHIFT);
  }
}

// --- AGG1 + GEMM2 fused ----------------------------------------------------
// h = relu(mean_j XL[j] + XR) in registers (16 lanes x float4/node), then
// HL = h@W2l^T, HR = h@W2r^T + b2l via in-group shfl_xor dot-reduce.
// Register accumulation + unroll-8 = 8 outstanding loads/lane (load-bearing;
// r11's LDS-accumulator variant collapsed MLP -> 12x slower).
__global__ __launch_bounds__(256) void k_agg1g2(const int* __restrict__ rs, const int* __restrict__ re,
                                                const int* __restrict__ csr_src,
                                                const float* __restrict__ XL, const float* __restrict__ XR,
                                                const float* __restrict__ W2l, const float* __restrict__ b2l,
                                                const float* __restrict__ W2r,
                                                float* __restrict__ HL, float* __restrict__ HR,
                                                int n_nodes) {
  int wave = threadIdx.x >> 6, lane = threadIdx.x & 63;
  int g = lane >> 4, c = lane & 15;
  int n = (blockIdx.x * 4 + wave) * 4 + g;
  if (n >= n_nodes) return;

  float4 wl0 = *(const float4*)(W2l + c * 4);
  float4 wl1 = *(const float4*)(W2l + 64 + c * 4);
  float4 wr0 = *(const float4*)(W2r + c * 4);
  float4 wr1 = *(const float4*)(W2r + 64 + c * 4);
  float4 xr = *(const float4*)(XR + (size_t)n * 64 + c * 4);

  int start = rs[n], end = re[n];
  float4 a0 = make_float4(0.f, 0.f, 0.f, 0.f);
  float4 a1 = make_float4(0.f, 0.f, 0.f, 0.f);
  float4 a2 = make_float4(0.f, 0.f, 0.f, 0.f);
  float4 a3 = make_float4(0.f, 0.f, 0.f, 0.f);
  int e = start;
  for (; e + 7 < end; e += 8) {               // unroll-8: 8 outstanding reads
    int s0 = csr_src[e],     s1 = csr_src[e + 1], s2 = csr_src[e + 2], s3 = csr_src[e + 3];
    int s4 = csr_src[e + 4], s5 = csr_src[e + 5], s6 = csr_src[e + 6], s7 = csr_src[e + 7];
    float4 v0 = *(const float4*)(XL + (size_t)s0 * 64 + c * 4);
    float4 v1 = *(const float4*)(XL + (size_t)s1 * 64 + c * 4);
    float4 v2 = *(const float4*)(XL + (size_t)s2 * 64 + c * 4);
    float4 v3 = *(const float4*)(XL + (size_t)s3 * 64 + c * 4);
    float4 v4 = *(const float4*)(XL + (size_t)s4 * 64 + c * 4);
    float4 v5 = *(const float4*)(XL + (size_t)s5 * 64 + c * 4);
    float4 v6 = *(const float4*)(XL + (size_t)s6 * 64 + c * 4);
    float4 v7 = *(const float4*)(XL + (size_t)s7 * 64 + c * 4);
    a0.x += v0.x; a0.y += v0.y; a0.z += v0.z; a0.w += v0.w;
    a1.x += v1.x; a1.y += v1.y; a1.z += v1.z; a1.w += v1.w;
    a2.x += v2.x; a2.y += v2.y; a2.z += v2.z; a2.w += v2.w;
    a3.x += v3.x; a3.y += v3.y; a3.z += v3.z; a3.w += v3.w;
    a0.x += v4.x; a0.y += v4.y; a0.z += v4.z; a0.w += v4.w;
    a1.x += v5.x; a1.y += v5.y; a1.z += v5.z; a1.w += v5.w;
    a2.x += v6.x; a2.y += v6.y; a2.z += v6.z; a2.w += v6.w;
    a3.x += v7.x; a3.y += v7.y; a3.z += v7.z; a3.w += v7.w;
  }
  for (; e + 3 < end; e += 4) {
    int s0 = csr_src[e], s1 = csr_src[e + 1], s2 = csr_src[e + 2], s3 = csr_src[e + 3];
    float4 v0 = *(const float4*)(XL + (size_t)s0 * 64 + c * 4);
    float4 v1 = *(const float4*)(XL + (size_t)s1 * 64 + c * 4);
    float4 v2 = *(const float4*)(XL + (size_t)s2 * 64 + c * 4);
    float4 v3 = *(const float4*)(XL + (size_t)s3 * 64 + c * 4);
    a0.x += v0.x; a0.y += v0.y; a0.z += v0.z; a0.w += v0.w;
    a1.x += v1.x; a1.y += v1.y; a1.z += v1.z; a1.w += v1.w;
    a2.x += v2.x; a2.y += v2.y; a2.z += v2.z; a2.w += v2.w;
    a3.x += v3.x; a3.y += v3.y; a3.z += v3.z; a3.w += v3.w;
  }
  if (e + 1 < end) {
    int s0 = csr_src[e], s1 = csr_src[e + 1];
    float4 v0 = *(const float4*)(XL + (size_t)s0 * 64 + c * 4);
    float4 v1 = *(const float4*)(XL + (size_t)s1 * 64 + c * 4);
    a0.x += v0.x; a0.y += v0.y; a0.z += v0.z; a0.w += v0.w;
    a1.x += v1.x; a1.y += v1.y; a1.z += v1.z; a1.w += v1.w;
    e += 2;
  }
  if (e < end) {
    int s0 = csr_src[e];
    float4 v0 = *(const float4*)(XL + (size_t)s0 * 64 + c * 4);
    a0.x += v0.x; a0.y += v0.y; a0.z += v0.z; a0.w += v0.w;
  }
  float inv = 1.0f / fmaxf((float)(end - start), 1.0f);
  float4 h;
  h.x = fmaxf((a0.x + a1.x + a2.x + a3.x) * inv + xr.x, 0.f);
  h.y = fmaxf((a0.y + a1.y + a2.y + a3.y) * inv + xr.y, 0.f);
  h.z = fmaxf((a0.z + a1.z + a2.z + a3.z) * inv + xr.z, 0.f);
  h.w = fmaxf((a0.w + a1.w + a2.w + a3.w) * inv + xr.w, 0.f);

  float p0 = h.x * wl0.x + h.y * wl0.y + h.z * wl0.z + h.w * wl0.w;
  float p1 = h.x * wl1.x + h.y * wl1.y + h.z * wl1.z + h.w * wl1.w;
  float q0 = h.x * wr0.x + h.y * wr0.y + h.z * wr0.z + h.w * wr0.w;
  float q1 = h.x * wr1.x + h.y * wr1.y + h.z * wr1.z + h.w * wr1.w;
#pragma unroll
  for (int off = 1; off < 16; off <<= 1) {
    p0 += __shfl_xor(p0, off, 16);
    p1 += __shfl_xor(p1, off, 16);
    q0 += __shfl_xor(q0, off, 16);
    q1 += __shfl_xor(q1, off, 16);
  }
  if (c == 0) {
    *(float2*)(HL + (size_t)n * 2) = make_float2(p0, p1);
    *(float2*)(HR + (size_t)n * 2) = make_float2(q0 + b2l[0], q1 + b2l[1]);
  }
}

// --- AGG2: out = mean_j HL[j] + HR  (thread per node, 2-dim features) ------
__global__ __launch_bounds__(256) void k_agg2(const int* __restrict__ rs, const int* __restrict__ re,
                                              const int* __restrict__ csr_src,
                                              const float* __restrict__ HL, const float* __restrict__ HR,
                                              float* __restrict__ out, int n_nodes) {
  int n = blockIdx.x * 256 + threadIdx.x;
  if (n >= n_nodes) return;
  int start = rs[n], end = re[n];
  float s0 = 0.f, s1 = 0.f;
  int e = start;
  for (; e + 1 < end; e += 2) {
    int sa = csr_src[e], sb = csr_src[e + 1];
    float2 va = *(const float2*)(HL + (size_t)sa * 2);
    float2 vb = *(const float2*)(HL + (size_t)sb * 2);
    s0 += va.x + vb.x; s1 += va.y + vb.y;
  }
  if (e < end) {
    int sa = csr_src[e];
    float2 va = *(const float2*)(HL + (size_t)sa * 2);
    s0 += va.x; s1 += va.y;
  }
  float inv = 1.0f / fmaxf((float)(end - start), 1.0f);
  float2 hr = *(const float2*)(HR + (size_t)n * 2);
  out[n * 2 + 0] = s0 * inv + hr.x;
  out[n * 2 + 1] = s1 * inv + hr.y;
}

// ---------------------------------------------------------------------------
extern "C" void kernel_launch(void* const* d_in, const int* in_sizes, int n_in,
                              void* d_out, int out_size, void* d_ws, size_t ws_size,
                              hipStream_t stream) {
  const float* x   = (const float*)d_in[0];
  const void*  eix = d_in[1];
  const float* W1l = (const float*)d_in[2];
  const float* b1l = (const float*)d_in[3];
  const float* W1r = (const float*)d_in[4];
  const float* W2l = (const float*)d_in[5];
  const float* b2l = (const float*)d_in[6];
  const float* W2r = (const float*)d_in[7];
  float* out = (float*)d_out;

  const int N = in_sizes[0] / 64;              // 100000
  const int E = in_sizes[1] / 2;               // 1600000
  const int NB = (N + 127) >> BKT_SHIFT;       // 782 buckets

  // workspace layout (256B-aligned chunks)
  char* base = (char*)d_ws;
  size_t off = 0;
  auto alloc = [&](size_t bytes) {
    char* p = base + off;
    off = (off + bytes + 255) & ~(size_t)255;
    return p;
  };
  int*   gcount  = (int*)alloc((size_t)BKT_MAX * 4);
  int*   rs      = (int*)alloc((size_t)N * 4);
  int*   re      = (int*)alloc((size_t)N * 4);
  int*   csr_src = (int*)alloc((size_t)NB * BKT_CAP * 4);   // 8.4 MB
  u32*   pairs   = (u32*)alloc((size_t)NB * BKT_CAP * 4);   // 8.4 MB
  float* XL      = (float*)alloc((size_t)N * 64 * 4);
  float* XR      = (float*)alloc((size_t)N * 64 * 4);
  float* HL      = (float*)alloc((size_t)N * 2 * 4);
  float* HR      = (float*)alloc((size_t)N * 2 * 4);
  (void)ws_size;

  const int nbkt = (E + CHUNK - 1) / CHUNK;    // 391 pass-A blocks
  const int ngem = (N + 63) / 64;              // 1563 gemm blocks

  hipMemsetAsync(gcount, 0, (size_t)BKT_MAX * 4, stream);
  k_pre<<<5 * nbkt, 256, 0, stream>>>(eix, gcount, pairs, E,
                                      x, W1l, b1l, W1r, XL, XR, N, nbkt, ngem);
  k_csr<<<NB, 512, 0, stream>>>(gcount, pairs, csr_src, rs, re, N);
  k_agg1g2<<<(N + 15) / 16, 256, 0, stream>>>(rs, re, csr_src, XL, XR, W2l, b2l, W2r, HL, HR, N);
  k_agg2<<<(N + 255) / 256, 256, 0, stream>>>(rs, re, csr_src, HL, HR, out, N);
}